// Round 11
// baseline (341.036 us; speedup 1.0000x reference)
//
#include <hip/hip_runtime.h>
#include <math.h>
#include <stdint.h>

// Problem constants
#define NB 64       // batch
#define NI 2048     // input capsules
#define NK 32       // output capsules
#define ND 16       // in_dim = out_dim

typedef _Float16 h2t   __attribute__((ext_vector_type(2)));
typedef _Float16 f16x4 __attribute__((ext_vector_type(4)));
typedef float    f32x4 __attribute__((ext_vector_type(4)));

#if defined(__has_builtin)
#if __has_builtin(__builtin_amdgcn_global_load_lds)
#define HAVE_GLL 1
#endif
#endif
#ifndef HAVE_GLL
#define HAVE_GLL 0
#endif

static __device__ __forceinline__ uint32_t pack_h2(float a, float b) {
    h2t p; p.x = (_Float16)a; p.y = (_Float16)b;
    return __builtin_bit_cast(uint32_t, p);
}

// lane ^ 16 exchange (within 32-lane halves) on the DS pipe
static __device__ __forceinline__ float swz_xor16(float x) {
    int v = __builtin_amdgcn_ds_swizzle(__builtin_bit_cast(int, x), 0x401F);
    return __builtin_bit_cast(float, v);
}
// full reduction over the 4 lane-quadrant groups (o-fragments)
static __device__ __forceinline__ float xreduce_o(float p) {
    p += swz_xor16(p);        // q ^= 1
    p += __shfl_xor(p, 32);   // q ^= 2
    return p;
}

// ---------------------------------------------------------------------------
// conv_w: W f32 [2048][32][16][16] -> MFMA A-fragment-ordered f16 units.
// Unit (8B) at Wh2[i*2048 + T*64 + l] = { W[i][T][4q+j][r] : j=0..3 } f16,
// q=l>>4, r=l&15  (A[m=o][k=d] layout for v_mfma_f32_16x16x16f16).
// ---------------------------------------------------------------------------
__global__ __launch_bounds__(256)
void conv_w(const float* __restrict__ Wg, uint32_t* __restrict__ Wh)
{
    __shared__ float tile[32 * 264];
    const int i = blockIdx.x;           // 0..2047
    const int t = threadIdx.x;
    const float4* src = (const float4*)(Wg + (size_t)i * 8192);
#pragma unroll
    for (int j = 0; j < 8; ++j) {
        const int f4 = t + j * 256;
        const int k  = f4 >> 6;
        const int r4 = f4 & 63;
        *(float4*)(&tile[k * 264 + r4 * 4]) = src[f4];
    }
    __syncthreads();
    const int T  = t >> 3;              // 0..31 (k-tile)
    const int l0 = (t & 7) * 8;
    const float* s = tile + T * 264;
    uint2* dst = (uint2*)(Wh + (size_t)i * 4096) + T * 64 + l0;
#pragma unroll
    for (int n = 0; n < 8; ++n) {
        const int l = l0 + n;
        const int q = l >> 4, r = l & 15;
        uint2 u;
        u.x = pack_h2(s[(4 * q + 0) * 16 + r], s[(4 * q + 1) * 16 + r]);
        u.y = pack_h2(s[(4 * q + 2) * 16 + r], s[(4 * q + 3) * 16 + r]);
        dst[n] = u;
    }
}

// ---------------------------------------------------------------------------
// conv_x: X f32 [64][2048][16] -> XT f16 d-pair-packed, transposed [2048][64][8].
// ---------------------------------------------------------------------------
__global__ __launch_bounds__(256)
void conv_x(const float* __restrict__ X, uint32_t* __restrict__ XT)
{
    const int g = blockIdx.x * 256 + threadIdx.x;   // 0..131071
    const int b = g >> 11, i = g & 2047;
    const float4* src = (const float4*)(X + ((size_t)b * 2048 + i) * 16);
    const float4 f0 = src[0], f1 = src[1], f2 = src[2], f3 = src[3];
    uint4 o0, o1;
    o0.x = pack_h2(f0.x, f0.y); o0.y = pack_h2(f0.z, f0.w);
    o0.z = pack_h2(f1.x, f1.y); o0.w = pack_h2(f1.z, f1.w);
    o1.x = pack_h2(f2.x, f2.y); o1.y = pack_h2(f2.z, f2.w);
    o1.z = pack_h2(f3.x, f3.y); o1.w = pack_h2(f3.z, f3.w);
    uint4* dst = (uint4*)(XT + (size_t)i * 512 + b * 8);
    dst[0] = o0; dst[1] = o1;
}

// ---------------------------------------------------------------------------
// MFMA fused routing pass — PAIR-TILE pipeline.
// Ring-2 of 32 KB double-slots (2 W tiles each); 8 iterations of 2 i's.
// Per iter: [vmcnt wait: pair landed] [s_barrier] [issue pair j+1 into slot
// freed by iter j-1] [compute 2 i's] [(VMODE1) one shared BAR_E].
// Wave w owns k-tiles [8w,8w+8); C-regs lane(q=l>>4,r=l&15):
//   um[tt][reg] = u_hat[b=r][k=8w+tt][o=4q+reg].
// Partials f16-pair-packed: part_h[slab][b16][k32][op8], slab = bg*128+ichunk.
// ---------------------------------------------------------------------------
template<int VMODE>
__global__ __launch_bounds__(256, 2)
void caps_pass_m(const uint32_t* __restrict__ XT,   // [2048][64][8] u32
                 const uint32_t* __restrict__ Wh,   // [2048][4096] u32 frag tiles
                 const float* __restrict__ V,       // [64][32][16] (VMODE=1)
                 uint32_t* __restrict__ part_h)     // f16-pair partials
{
    constexpr int IC = 16;             // i's per block
    constexpr int NP = IC / 2;         // 8 pair-iterations
    __shared__ uint32_t Ws[2][2][4096]; // 2 slots x 2 tiles x 16 KB
    __shared__ uint32_t Xs[2048];       // [ig16][b16][dp8] 8 KB
    __shared__ float    Ep[2][4][16];   // per-i-in-pair, per-wave esum partials

    const int t = threadIdx.x;
    const int l = t & 63;
    const int w = t >> 6;              // wave id -> k-tiles [8w, 8w+8)
    const int r = l & 15;              // b-in-block
    const int q = l >> 4;              // o-quad

    const int wg     = blockIdx.x;     // 0..511
    const int xcd    = wg & 7;
    const int slot   = wg >> 3;        // 0..63
    const int ichunk = xcd * 16 + (slot >> 2);   // 0..127
    const int bg     = slot & 3;
    const int i0 = ichunk * IC;
    const int b0 = bg * 16;

    f32x4 s_acc[8];
#pragma unroll
    for (int tt = 0; tt < 8; ++tt) s_acc[tt] = (f32x4){0.f, 0.f, 0.f, 0.f};

    f32x4 v_r[8];
    if constexpr (VMODE == 1) {
#pragma unroll
        for (int tt = 0; tt < 8; ++tt)
            v_r[tt] = *(const f32x4*)(V + ((size_t)(b0 + r) * NK + (8 * w + tt)) * 16 + 4 * q);
    }

    // ---- stage X chunk: Xs[ig][b][dp] (8 KB) ----
    {
        const int ig = t >> 4, uu = t & 15;
        const uint4* src = (const uint4*)(XT + (size_t)(i0 + ig) * 512 + b0 * 8);
        *(uint4*)&Xs[ig * 128 + uu * 4]        = src[uu];
        *(uint4*)&Xs[ig * 128 + (uu + 16) * 4] = src[uu + 16];
    }

    // stage one W tile into Ws[sl][half] (4 loads / thread)
#if HAVE_GLL
#define STAGE_T(sl, half, tile)                                                \
    {                                                                          \
        const size_t ibase_ = (size_t)(tile) * 4096;                           \
        _Pragma("unroll")                                                      \
        for (int j = 0; j < 4; ++j) {                                          \
            const int p = w * 4 + j;                                           \
            __builtin_amdgcn_global_load_lds(                                  \
                (const __attribute__((address_space(1))) void*)(Wh + ibase_ + p * 256 + l * 4), \
                (__attribute__((address_space(3))) void*)&Ws[sl][half][p * 256], 16, 0, 0); \
        }                                                                      \
    }
#define BAR_W(n) asm volatile("s_waitcnt vmcnt(" #n ")\ns_barrier" ::: "memory");
#else
#define STAGE_T(sl, half, tile)                                                \
    {                                                                          \
        const size_t ibase_ = (size_t)(tile) * 4096;                           \
        _Pragma("unroll")                                                      \
        for (int j = 0; j < 4; ++j) {                                          \
            const int p = w * 4 + j;                                           \
            ((uint4*)&Ws[sl][half][p * 256])[l] = *(const uint4*)(Wh + ibase_ + p * 256 + l * 4); \
        }                                                                      \
    }
#define BAR_W(n) asm volatile("s_waitcnt vmcnt(0) lgkmcnt(0)\ns_barrier" ::: "memory");
#endif
#define BAR_E() asm volatile("s_waitcnt lgkmcnt(0)\ns_barrier" ::: "memory");

    __syncthreads();   // Xs visible; clean vmcnt point

    // prologue: pair 0 -> slot 0, pair 1 -> slot 1
    STAGE_T(0, 0, i0 + 0) STAGE_T(0, 1, i0 + 1)
    STAGE_T(1, 0, i0 + 2) STAGE_T(1, 1, i0 + 3)

#pragma unroll
    for (int j = 0; j < NP; ++j) {
        const int s = j & 1;
        // gate: this iter's pair landed. j=0: 16 outstanding, drain oldest 8.
        if (j == 0) { BAR_W(8) } else { BAR_W(0) }

        // issue pair j+1 into the slot freed by iter j-1 (slot (j+1)&1)
        if (j >= 1 && j + 1 < NP) {
            const int ns = (j + 1) & 1;
            const int nt = i0 + 2 * (j + 1);
            STAGE_T(ns, 0, nt) STAGE_T(ns, 1, nt + 1)
        }

        if constexpr (VMODE == 0) {
#pragma unroll
            for (int ia = 0; ia < 2; ++ia) {
                const int ii = 2 * j + ia;
                const f16x4 xb = *(const f16x4*)&Xs[ii * 128 + r * 8 + q * 2];
#pragma unroll
                for (int tt = 0; tt < 8; ++tt) {
                    const f16x4 a = *(const f16x4*)&Ws[s][ia][(w * 8 + tt) * 128 + l * 2];
                    s_acc[tt] = __builtin_amdgcn_mfma_f32_16x16x16f16(a, xb, s_acc[tt], 0, 0, 0);
                }
            }
        } else {
            f32x4 um[2][8];
            float e[2][8];
#pragma unroll
            for (int ia = 0; ia < 2; ++ia) {
                const int ii = 2 * j + ia;
                const f16x4 xb = *(const f16x4*)&Xs[ii * 128 + r * 8 + q * 2];
#pragma unroll
                for (int tt = 0; tt < 8; ++tt) {
                    const f16x4 a = *(const f16x4*)&Ws[s][ia][(w * 8 + tt) * 128 + l * 2];
                    um[ia][tt] = __builtin_amdgcn_mfma_f32_16x16x16f16(
                        a, xb, (f32x4){0.f, 0.f, 0.f, 0.f}, 0, 0, 0);
                }
                float esp = 0.f;
#pragma unroll
                for (int tt = 0; tt < 8; ++tt) {
                    float p = um[ia][tt][0] * v_r[tt][0];
                    p = fmaf(um[ia][tt][1], v_r[tt][1], p);
                    p = fmaf(um[ia][tt][2], v_r[tt][2], p);
                    p = fmaf(um[ia][tt][3], v_r[tt][3], p);
                    p = xreduce_o(p);                 // full sum over o
                    e[ia][tt] = __expf(p);            // |lg| small: no max-sub
                    esp += e[ia][tt];
                }
                if (q == 0) Ep[ia][w][r] = esp;
            }
            BAR_E();                                  // one barrier for both i's
#pragma unroll
            for (int ia = 0; ia < 2; ++ia) {
                const float es = Ep[ia][0][r] + Ep[ia][1][r]
                               + Ep[ia][2][r] + Ep[ia][3][r];
                const float ci = __builtin_amdgcn_rcpf(es);
#pragma unroll
                for (int tt = 0; tt < 8; ++tt) {
                    const float c = e[ia][tt] * ci;
                    s_acc[tt][0] = fmaf(c, um[ia][tt][0], s_acc[tt][0]);
                    s_acc[tt][1] = fmaf(c, um[ia][tt][1], s_acc[tt][1]);
                    s_acc[tt][2] = fmaf(c, um[ia][tt][2], s_acc[tt][2]);
                    s_acc[tt][3] = fmaf(c, um[ia][tt][3], s_acc[tt][3]);
                }
            }
        }
    }
#undef STAGE_T
#undef BAR_W
#undef BAR_E

    // ---- store f16-pair partial tile: part_h[slab][b=r][k=8w+tt][op=2q,2q+1] ----
    uint32_t* base = part_h + (size_t)(bg * 128 + ichunk) * 4096 + r * 256 + 2 * q;
#pragma unroll
    for (int tt = 0; tt < 8; ++tt) {
        uint2 st;
        st.x = pack_h2(s_acc[tt][0], s_acc[tt][1]);
        st.y = pack_h2(s_acc[tt][2], s_acc[tt][3]);
        *(uint2*)(base + (8 * w + tt) * 8) = st;
    }
}

// ---------------------------------------------------------------------------
// Reduce 128 f16-pair slabs per output pair + fused squash / v production.
// Output pair j in [0,16384): b=j>>8, k=(j>>3)&31, op=j&7 (o=2op,2op+1).
// RMODE=0: s0 = sum; store s0 (f32); v0 = squash(s0/32)
// RMODE=1: v01 = squash(S0red/32) + squash(sum)
// RMODE=2: out = squash(sum)
// ---------------------------------------------------------------------------
template<int RMODE>
__global__ __launch_bounds__(256)
void caps_reduce(const uint32_t* __restrict__ part_h,
                 const float* __restrict__ S0red,
                 float* __restrict__ S0out,
                 float* __restrict__ Vout)
{
    __shared__ float2 red[4][64];
    const int t   = threadIdx.x;
    const int jl  = t & 63;
    const int qc  = t >> 6;
    const int jb  = blockIdx.x * 64;     // pair base
    const int j   = jb + jl;             // 0..16383
    const int b   = j >> 8;
    const int bg  = b >> 4;
    const int loc = (b & 15) * 256 + (j & 255);
    const uint32_t* p = part_h + ((size_t)(bg * 128 + qc * 32)) * 4096 + loc;
    float sx = 0.f, sy = 0.f;
#pragma unroll 8
    for (int ic = 0; ic < 32; ++ic) {
        h2t v = __builtin_bit_cast(h2t, p[(size_t)ic * 4096]);
        sx += (float)v.x; sy += (float)v.y;
    }
    red[qc][jl] = make_float2(sx, sy);
    __syncthreads();
    if (t < 64) {
        const int jj = jb + t;
        float2 a0 = red[0][t], a1 = red[1][t], a2 = red[2][t], a3 = red[3][t];
        const float tx = a0.x + a1.x + a2.x + a3.x;
        const float ty = a0.y + a1.y + a2.y + a3.y;
        if constexpr (RMODE == 0) {
            S0out[2 * jj]     = tx;
            S0out[2 * jj + 1] = ty;
            const float vx = tx * (1.0f / 32.0f), vy = ty * (1.0f / 32.0f);
            float sq = vx * vx + vy * vy;
#pragma unroll
            for (int mask = 4; mask >= 1; mask >>= 1) sq += __shfl_xor(sq, mask);
            const float sc = sqrtf(sq) / (1.0f + sq);
            Vout[2 * jj]     = vx * sc;
            Vout[2 * jj + 1] = vy * sc;
        } else if constexpr (RMODE == 1) {
            const float v0x = S0red[2 * jj] * (1.0f / 32.0f);
            const float v0y = S0red[2 * jj + 1] * (1.0f / 32.0f);
            float sq0 = v0x * v0x + v0y * v0y;
#pragma unroll
            for (int mask = 4; mask >= 1; mask >>= 1) sq0 += __shfl_xor(sq0, mask);
            const float sc0 = sqrtf(sq0) / (1.0f + sq0);
            float sq1 = tx * tx + ty * ty;
#pragma unroll
            for (int mask = 4; mask >= 1; mask >>= 1) sq1 += __shfl_xor(sq1, mask);
            const float sc1 = sqrtf(sq1) / (1.0f + sq1);
            Vout[2 * jj]     = fmaf(v0x, sc0, tx * sc1);
            Vout[2 * jj + 1] = fmaf(v0y, sc0, ty * sc1);
        } else {
            float sq = tx * tx + ty * ty;
#pragma unroll
            for (int mask = 4; mask >= 1; mask >>= 1) sq += __shfl_xor(sq, mask);
            const float sc = sqrtf(sq) / (1.0f + sq);
            Vout[2 * jj]     = tx * sc;
            Vout[2 * jj + 1] = ty * sc;
        }
    }
}

// ===========================================================================
// Fallback (small ws): proven R1-style f32 atomic path.
// ===========================================================================
template<int VMODE>
__global__ __launch_bounds__(256, 4)
void caps_pass_f32(const float* __restrict__ X,
                   const float* __restrict__ Wg,
                   const float* __restrict__ S0,
                   const float* __restrict__ S1,
                   float* __restrict__ Sout)
{
    constexpr int IC = 8;
    __shared__ float Ws[8192];
    __shared__ float Xs[2048];

    const int t   = threadIdx.x;
    const int kk  = t & 31;
    const int oh  = (t >> 5) & 1;
    const int bq4 = t >> 6;

    const int wg     = blockIdx.x;
    const int xcd    = wg & 7;
    const int slot   = wg >> 3;
    const int ichunk = xcd * 32 + (slot >> 2);
    const int bg     = slot & 3;
    const int i0 = ichunk * IC;
    const int b0 = bg * 16;

    float s_acc[4][8];
#pragma unroll
    for (int bb = 0; bb < 4; ++bb)
#pragma unroll
        for (int o = 0; o < 8; ++o) s_acc[bb][o] = 0.f;

    float v_r[4][8];
    if constexpr (VMODE >= 1) {
#pragma unroll
        for (int bb = 0; bb < 4; ++bb) {
            const int b = b0 + bq4 * 4 + bb;
            const float* p0 = S0 + ((size_t)b * NK + kk) * 16 + oh * 8;
            float4 a = *(const float4*)(p0);
            float4 c = *(const float4*)(p0 + 4);
            float val0[8] = {a.x,a.y,a.z,a.w,c.x,c.y,c.z,c.w};
            float sq0 = 0.f;
#pragma unroll
            for (int o = 0; o < 8; ++o) { val0[o] *= (1.0f/32.0f); sq0 = fmaf(val0[o], val0[o], sq0); }
            sq0 += __shfl_xor(sq0, 32);
            const float sc0 = sqrtf(sq0) / (1.0f + sq0);
#pragma unroll
            for (int o = 0; o < 8; ++o) v_r[bb][o] = val0[o] * sc0;
            if constexpr (VMODE == 2) {
                const float* p1 = S1 + ((size_t)b * NK + kk) * 16 + oh * 8;
                float4 a1 = *(const float4*)(p1);
                float4 c1 = *(const float4*)(p1 + 4);
                float val1[8] = {a1.x,a1.y,a1.z,a1.w,c1.x,c1.y,c1.z,c1.w};
                float sq1 = 0.f;
#pragma unroll
                for (int o = 0; o < 8; ++o) sq1 = fmaf(val1[o], val1[o], sq1);
                sq1 += __shfl_xor(sq1, 32);
                const float sc1 = sqrtf(sq1) / (1.0f + sq1);
#pragma unroll
                for (int o = 0; o < 8; ++o) v_r[bb][o] = fmaf(val1[o], sc1, v_r[bb][o]);
            }
        }
    }

    {
        const int xb   = t >> 4;
        const int xig  = t & 7;
        const int half = (t >> 3) & 1;
        const float* xp = X + (size_t)(b0 + xb) * (NI * ND) + (size_t)(i0 + xig) * ND + half * 8;
        float4 f0 = *(const float4*)(xp);
        float4 f1 = *(const float4*)(xp + 4);
        float vals[8] = {f0.x,f0.y,f0.z,f0.w,f1.x,f1.y,f1.z,f1.w};
        const int m = (xig & 7) << 3;
#pragma unroll
        for (int jj = 0; jj < 8; ++jj) {
            const int d = half * 8 + jj;
            Xs[xig * 256 + ((16 * d + xb) ^ m)] = vals[jj];
        }
    }

    for (int ii = 0; ii < IC; ++ii) {
        const int i = i0 + ii;
        __syncthreads();
        {
            const float4* wsrc = (const float4*)(Wg + (size_t)i * 8192);
#pragma unroll
            for (int j = 0; j < 8; ++j) {
                float4 val = wsrc[t + j * 256];
                const int k = (t >> 6) + 4 * j;
                ((float4*)Ws)[k * 64 + ((t & 63) ^ (k & 7))] = val;
            }
        }
        __syncthreads();

        const int xm = (ii & 7) << 3;
        float u[4][8];
        if constexpr (VMODE >= 1) {
#pragma unroll
            for (int bb = 0; bb < 4; ++bb)
#pragma unroll
                for (int o = 0; o < 8; ++o) u[bb][o] = 0.f;
        }
#pragma unroll
        for (int d = 0; d < 16; ++d) {
            const float4 x4 = *(const float4*)(&Xs[ii * 256 + ((16 * d + 4 * bq4) ^ xm)]);
            float wvv[8];
            {
                const float4 wA = ((const float4*)Ws)[kk * 64 + ((d * 4 + oh * 2)     ^ (kk & 7))];
                const float4 wB = ((const float4*)Ws)[kk * 64 + ((d * 4 + oh * 2 + 1) ^ (kk & 7))];
                wvv[0]=wA.x; wvv[1]=wA.y; wvv[2]=wA.z; wvv[3]=wA.w;
                wvv[4]=wB.x; wvv[5]=wB.y; wvv[6]=wB.z; wvv[7]=wB.w;
            }
            if constexpr (VMODE >= 1) {
#pragma unroll
                for (int o = 0; o < 8; ++o) {
                    u[0][o] = fmaf(x4.x, wvv[o], u[0][o]);
                    u[1][o] = fmaf(x4.y, wvv[o], u[1][o]);
                    u[2][o] = fmaf(x4.z, wvv[o], u[2][o]);
                    u[3][o] = fmaf(x4.w, wvv[o], u[3][o]);
                }
            } else {
#pragma unroll
                for (int o = 0; o < 8; ++o) {
                    s_acc[0][o] = fmaf(x4.x, wvv[o], s_acc[0][o]);
                    s_acc[1][o] = fmaf(x4.y, wvv[o], s_acc[1][o]);
                    s_acc[2][o] = fmaf(x4.z, wvv[o], s_acc[2][o]);
                    s_acc[3][o] = fmaf(x4.w, wvv[o], s_acc[3][o]);
                }
            }
        }

        if constexpr (VMODE >= 1) {
#pragma unroll
            for (int bb = 0; bb < 4; ++bb) {
                float lg = 0.f;
#pragma unroll
                for (int o = 0; o < 8; ++o) lg = fmaf(u[bb][o], v_r[bb][o], lg);
                lg += __shfl_xor(lg, 32);
                float m = lg;
#pragma unroll
                for (int mask = 16; mask >= 1; mask >>= 1)
                    m = fmaxf(m, __shfl_xor(m, mask));
                const float e = __expf(lg - m);
                float ssum = e;
#pragma unroll
                for (int mask = 16; mask >= 1; mask >>= 1)
                    ssum += __shfl_xor(ssum, mask);
                const float c = e / ssum;
#pragma unroll
                for (int o = 0; o < 8; ++o)
                    s_acc[bb][o] = fmaf(c, u[bb][o], s_acc[bb][o]);
            }
        }
    }

#pragma unroll
    for (int bb = 0; bb < 4; ++bb) {
        float* sp = Sout + ((size_t)(b0 + bq4 * 4 + bb) * NK + kk) * 16 + oh * 8;
#pragma unroll
        for (int o = 0; o < 8; ++o) atomicAdd(sp + o, s_acc[bb][o]);
    }
}

__global__ __launch_bounds__(256)
void squash_kernel(const float* __restrict__ S, float* __restrict__ Vout)
{
    const int idx = blockIdx.x * 256 + threadIdx.x;
    float val = S[idx];
    float sq = val * val;
#pragma unroll
    for (int mask = 8; mask >= 1; mask >>= 1) sq += __shfl_xor(sq, mask);
    const float sc = sqrtf(sq) / (1.0f + sq);
    Vout[idx] = val * sc;
}

extern "C" void kernel_launch(void* const* d_in, const int* in_sizes, int n_in,
                              void* d_out, int out_size, void* d_ws, size_t ws_size,
                              hipStream_t stream)
{
    const float* X  = (const float*)d_in[0];   // [64][2048][16]
    const float* Wg = (const float*)d_in[1];   // [2048][32][16][16]
    float* out = (float*)d_out;                // [64][32][16]

    const size_t WHU   = (size_t)2048 * 4096;       // u32
    const size_t XHU   = (size_t)64 * 2048 * 8;     // u32
    const size_t PARTU = (size_t)512 * 4096;        // u32 (f16-pair partials)
    const size_t need  = (WHU + XHU + PARTU) * 4 + 3 * 32768 * 4;  // ~44.5 MB

    const dim3 blk(256), pgrid(512), rgrid(256);

    if (ws_size >= need) {
        uint32_t* Wh   = (uint32_t*)d_ws;
        uint32_t* XT   = Wh + WHU;
        uint32_t* part = XT + XHU;
        float* s0      = (float*)(part + PARTU);
        float* v0      = s0 + 32768;
        float* v01     = v0 + 32768;

        conv_w<<<dim3(2048), blk, 0, stream>>>(Wg, Wh);
        conv_x<<<dim3(512),  blk, 0, stream>>>(X, XT);

        caps_pass_m<0><<<pgrid, blk, 0, stream>>>(XT, Wh, nullptr, part);
        caps_reduce<0><<<rgrid, blk, 0, stream>>>(part, nullptr, s0, v0);
        caps_pass_m<1><<<pgrid, blk, 0, stream>>>(XT, Wh, v0, part);
        caps_reduce<1><<<rgrid, blk, 0, stream>>>(part, s0, nullptr, v01);
        caps_pass_m<1><<<pgrid, blk, 0, stream>>>(XT, Wh, v01, part);
        caps_reduce<2><<<rgrid, blk, 0, stream>>>(part, nullptr, nullptr, out);
    } else {
        // fallback: f32 atomic path
        float* s0 = (float*)d_ws;
        float* s1 = s0 + 32768;
        float* s2 = s1 + 32768;
        hipMemsetAsync(d_ws, 0, (size_t)3 * 32768 * sizeof(float), stream);
        caps_pass_f32<0><<<dim3(1024), blk, 0, stream>>>(X, Wg, nullptr, nullptr, s0);
        caps_pass_f32<1><<<dim3(1024), blk, 0, stream>>>(X, Wg, s0, nullptr, s1);
        caps_pass_f32<2><<<dim3(1024), blk, 0, stream>>>(X, Wg, s0, s1, s2);
        squash_kernel<<<dim3(128), blk, 0, stream>>>(s2, out);
    }
}

// Round 12
// 96.711 us; speedup vs baseline: 3.5263x; 3.5263x over previous
//
#include <hip/hip_runtime.h>
#include <math.h>
#include <stdint.h>

// Problem constants
#define NB 64       // batch
#define NI 2048     // input capsules
#define NK 32       // output capsules
#define ND 16       // in_dim = out_dim

typedef _Float16 h2t   __attribute__((ext_vector_type(2)));
typedef _Float16 f16x4 __attribute__((ext_vector_type(4)));
typedef float    f32x4 __attribute__((ext_vector_type(4)));

#if defined(__has_builtin)
#if __has_builtin(__builtin_amdgcn_global_load_lds)
#define HAVE_GLL 1
#endif
#endif
#ifndef HAVE_GLL
#define HAVE_GLL 0
#endif

static __device__ __forceinline__ uint32_t pack_h2(float a, float b) {
    h2t p; p.x = (_Float16)a; p.y = (_Float16)b;
    return __builtin_bit_cast(uint32_t, p);
}

// lane ^ 16 exchange (within 32-lane halves) on the DS pipe
static __device__ __forceinline__ float swz_xor16(float x) {
    int v = __builtin_amdgcn_ds_swizzle(__builtin_bit_cast(int, x), 0x401F);
    return __builtin_bit_cast(float, v);
}
// full reduction over the 4 lane-quadrant groups (o-fragments)
static __device__ __forceinline__ float xreduce_o(float p) {
    p += swz_xor16(p);        // q ^= 1
    p += __shfl_xor(p, 32);   // q ^= 2
    return p;
}

// ---------------------------------------------------------------------------
// conv_w: W f32 [2048][32][16][16] -> MFMA A-fragment-ordered f16 units.
// Unit (8B) at Wh2[i*2048 + T*64 + l] = { W[i][T][4q+j][r] : j=0..3 } f16,
// q=l>>4, r=l&15  (A[m=o][k=d] layout for v_mfma_f32_16x16x16f16).
// ---------------------------------------------------------------------------
__global__ __launch_bounds__(256)
void conv_w(const float* __restrict__ Wg, uint32_t* __restrict__ Wh)
{
    __shared__ float tile[32 * 264];
    const int i = blockIdx.x;           // 0..2047
    const int t = threadIdx.x;
    const float4* src = (const float4*)(Wg + (size_t)i * 8192);
#pragma unroll
    for (int j = 0; j < 8; ++j) {
        const int f4 = t + j * 256;
        const int k  = f4 >> 6;
        const int r4 = f4 & 63;
        *(float4*)(&tile[k * 264 + r4 * 4]) = src[f4];
    }
    __syncthreads();
    const int T  = t >> 3;              // 0..31 (k-tile)
    const int l0 = (t & 7) * 8;
    const float* s = tile + T * 264;
    uint2* dst = (uint2*)(Wh + (size_t)i * 4096) + T * 64 + l0;
#pragma unroll
    for (int n = 0; n < 8; ++n) {
        const int l = l0 + n;
        const int q = l >> 4, r = l & 15;
        uint2 u;
        u.x = pack_h2(s[(4 * q + 0) * 16 + r], s[(4 * q + 1) * 16 + r]);
        u.y = pack_h2(s[(4 * q + 2) * 16 + r], s[(4 * q + 3) * 16 + r]);
        dst[n] = u;
    }
}

// ---------------------------------------------------------------------------
// conv_x: X f32 [64][2048][16] -> XT f16 d-pair-packed, transposed [2048][64][8].
// ---------------------------------------------------------------------------
__global__ __launch_bounds__(256)
void conv_x(const float* __restrict__ X, uint32_t* __restrict__ XT)
{
    const int g = blockIdx.x * 256 + threadIdx.x;   // 0..131071
    const int b = g >> 11, i = g & 2047;
    const float4* src = (const float4*)(X + ((size_t)b * 2048 + i) * 16);
    const float4 f0 = src[0], f1 = src[1], f2 = src[2], f3 = src[3];
    uint4 o0, o1;
    o0.x = pack_h2(f0.x, f0.y); o0.y = pack_h2(f0.z, f0.w);
    o0.z = pack_h2(f1.x, f1.y); o0.w = pack_h2(f1.z, f1.w);
    o1.x = pack_h2(f2.x, f2.y); o1.y = pack_h2(f2.z, f2.w);
    o1.z = pack_h2(f3.x, f3.y); o1.w = pack_h2(f3.z, f3.w);
    uint4* dst = (uint4*)(XT + (size_t)i * 512 + b * 8);
    dst[0] = o0; dst[1] = o1;
}

// ---------------------------------------------------------------------------
// MFMA fused routing pass. Ring-3 W staging (global_load_lds, counted vmcnt).
// IC=16, grid 512 (= 2 blocks/CU, all resident, no tail).
// Per i: u_hat tile via v_mfma_f32_16x16x16f16; wave w owns k-tiles [8w,8w+8).
// C-regs lane(q=l>>4, r=l&15): u[tt][reg] = u_hat[b=r][k=8w+tt][o=4q+reg].
// VMODE=0: s_acc = mfma-accumulate over i (1 barrier/iter).
// VMODE=1: logit=dot4+o-reduce; e=exp; cross-wave esum via Ep + lgkm barrier.
// Partials stored f16-pair-packed: part_h[slab][b16][k32][op8] u32,
// slab = bg*128 + ichunk.
// ---------------------------------------------------------------------------
template<int VMODE>
__global__ __launch_bounds__(256, 2)
void caps_pass_m(const uint32_t* __restrict__ XT,   // [2048][64][8] u32
                 const uint32_t* __restrict__ Wh,   // [2048][4096] u32 frag tiles
                 const float* __restrict__ V,       // [64][32][16] (VMODE=1)
                 uint32_t* __restrict__ part_h)     // f16-pair partials
{
    constexpr int IC = 16;
    __shared__ uint32_t Ws[3][4096];   // 3 x 16 KB W ring
    __shared__ uint32_t Xs[2048];      // [ig16][b16][dp8] 8 KB
    __shared__ float    Ep[2][4][16];  // per-wave esum partials, dbuf

    const int t = threadIdx.x;
    const int l = t & 63;
    const int w = t >> 6;              // wave id -> k-tiles [8w, 8w+8)
    const int r = l & 15;              // b-in-block
    const int q = l >> 4;              // o-quad

    const int wg     = blockIdx.x;     // 0..511
    const int xcd    = wg & 7;
    const int slot   = wg >> 3;        // 0..63
    const int ichunk = xcd * 16 + (slot >> 2);   // 0..127
    const int bg     = slot & 3;
    const int i0 = ichunk * IC;
    const int b0 = bg * 16;

    f32x4 s_acc[8];
#pragma unroll
    for (int tt = 0; tt < 8; ++tt) s_acc[tt] = (f32x4){0.f, 0.f, 0.f, 0.f};

    f32x4 v_r[8];
    if constexpr (VMODE == 1) {
#pragma unroll
        for (int tt = 0; tt < 8; ++tt)
            v_r[tt] = *(const f32x4*)(V + ((size_t)(b0 + r) * NK + (8 * w + tt)) * 16 + 4 * q);
    }

    // ---- stage X chunk: Xs[ig][b][dp] (8 KB) ----
    {
        const int ig = t >> 4, uu = t & 15;
        const uint4* src = (const uint4*)(XT + (size_t)(i0 + ig) * 512 + b0 * 8);
        *(uint4*)&Xs[ig * 128 + uu * 4]        = src[uu];
        *(uint4*)&Xs[ig * 128 + (uu + 16) * 4] = src[uu + 16];
    }

#define STAGE_W(buf, tile)                                                     \
    {                                                                          \
        const size_t ibase_ = (size_t)(tile) * 4096;                           \
        _Pragma("unroll")                                                      \
        for (int j = 0; j < 4; ++j) {                                          \
            const int p = w * 4 + j;                                           \
            STAGE_ONE(buf, ibase_, p)                                          \
        }                                                                      \
    }
#if HAVE_GLL
#define STAGE_ONE(buf, ibase_, p)                                              \
    __builtin_amdgcn_global_load_lds(                                          \
        (const __attribute__((address_space(1))) void*)(Wh + ibase_ + (p) * 256 + l * 4), \
        (__attribute__((address_space(3))) void*)&Ws[buf][(p) * 256], 16, 0, 0);
#define BAR_W(n) asm volatile("s_waitcnt vmcnt(" #n ")\ns_barrier" ::: "memory");
#else
#define STAGE_ONE(buf, ibase_, p)                                              \
    ((uint4*)&Ws[buf][(p) * 256])[l] = *(const uint4*)(Wh + ibase_ + (p) * 256 + l * 4);
#define BAR_W(n) asm volatile("s_waitcnt vmcnt(0) lgkmcnt(0)\ns_barrier" ::: "memory");
#endif
#define BAR_E() asm volatile("s_waitcnt lgkmcnt(0)\ns_barrier" ::: "memory");

    __syncthreads();   // Xs visible; clean vmcnt point

    // prologue: tiles i0, i0+1
    STAGE_W(0, i0)
    STAGE_W(1, i0 + 1)

    int cur = 0;
    for (int ii = 0; ii < IC; ++ii) {
        if (ii + 1 < IC) { BAR_W(4) } else { BAR_W(0) }

        if (ii + 2 < IC) {
            const int nslot = (cur + 2 >= 3) ? cur - 1 : cur + 2;
            STAGE_W(nslot, i0 + ii + 2)
        }

        // ---- fragments ----
        const f16x4 xb = *(const f16x4*)&Xs[ii * 128 + r * 8 + q * 2];

        if constexpr (VMODE == 0) {
#pragma unroll
            for (int tt = 0; tt < 8; ++tt) {
                const f16x4 a = *(const f16x4*)&Ws[cur][(w * 8 + tt) * 128 + l * 2];
                s_acc[tt] = __builtin_amdgcn_mfma_f32_16x16x16f16(a, xb, s_acc[tt], 0, 0, 0);
            }
        } else {
            f32x4 um[8];
#pragma unroll
            for (int tt = 0; tt < 8; ++tt) {
                const f16x4 a = *(const f16x4*)&Ws[cur][(w * 8 + tt) * 128 + l * 2];
                um[tt] = __builtin_amdgcn_mfma_f32_16x16x16f16(
                    a, xb, (f32x4){0.f, 0.f, 0.f, 0.f}, 0, 0, 0);
            }
            // ---- logits + exp + per-wave esum partial ----
            float e[8];
            float esp = 0.f;
#pragma unroll
            for (int tt = 0; tt < 8; ++tt) {
                float p = um[tt][0] * v_r[tt][0];
                p = fmaf(um[tt][1], v_r[tt][1], p);
                p = fmaf(um[tt][2], v_r[tt][2], p);
                p = fmaf(um[tt][3], v_r[tt][3], p);
                p = xreduce_o(p);                 // full sum over o
                e[tt] = __expf(p);                // |lg| small: no max-sub
                esp += e[tt];
            }
            if (q == 0) Ep[ii & 1][w][r] = esp;
            BAR_E();                              // lgkm only: W prefetch stays in flight
            const float es = Ep[ii & 1][0][r] + Ep[ii & 1][1][r]
                           + Ep[ii & 1][2][r] + Ep[ii & 1][3][r];
            const float ci = __builtin_amdgcn_rcpf(es);
#pragma unroll
            for (int tt = 0; tt < 8; ++tt) {
                const float c = e[tt] * ci;
                s_acc[tt][0] = fmaf(c, um[tt][0], s_acc[tt][0]);
                s_acc[tt][1] = fmaf(c, um[tt][1], s_acc[tt][1]);
                s_acc[tt][2] = fmaf(c, um[tt][2], s_acc[tt][2]);
                s_acc[tt][3] = fmaf(c, um[tt][3], s_acc[tt][3]);
            }
        }
        cur = (cur == 2) ? 0 : cur + 1;
    }
#undef STAGE_W
#undef STAGE_ONE
#undef BAR_W
#undef BAR_E

    // ---- store f16-pair partial tile: part_h[slab][b=r][k=8w+tt][op=2q,2q+1] ----
    uint32_t* base = part_h + (size_t)(bg * 128 + ichunk) * 4096 + r * 256 + 2 * q;
#pragma unroll
    for (int tt = 0; tt < 8; ++tt) {
        uint2 st;
        st.x = pack_h2(s_acc[tt][0], s_acc[tt][1]);
        st.y = pack_h2(s_acc[tt][2], s_acc[tt][3]);
        *(uint2*)(base + (8 * w + tt) * 8) = st;
    }
}

// ---------------------------------------------------------------------------
// Reduce 128 f16-pair slabs per output pair + fused squash / v production.
// Output pair j in [0,16384): b=j>>8, k=(j>>3)&31, op=j&7 (o=2op,2op+1).
// RMODE=0: s0 = sum; store s0 (f32); v0 = squash(s0/32)
// RMODE=1: v01 = squash(S0red/32) + squash(sum)
// RMODE=2: out = squash(sum)
// Grid 256 x 256: block owns 64 pairs; thread (jl=t&63, qc=t>>6) sums 32 slabs.
// ---------------------------------------------------------------------------
template<int RMODE>
__global__ __launch_bounds__(256)
void caps_reduce(const uint32_t* __restrict__ part_h,
                 const float* __restrict__ S0red,
                 float* __restrict__ S0out,
                 float* __restrict__ Vout)
{
    __shared__ float2 red[4][64];
    const int t   = threadIdx.x;
    const int jl  = t & 63;
    const int qc  = t >> 6;
    const int jb  = blockIdx.x * 64;     // pair base
    const int j   = jb + jl;             // 0..16383
    const int b   = j >> 8;
    const int bg  = b >> 4;
    const int loc = (b & 15) * 256 + (j & 255);
    const uint32_t* p = part_h + ((size_t)(bg * 128 + qc * 32)) * 4096 + loc;
    float sx = 0.f, sy = 0.f;
#pragma unroll 8
    for (int ic = 0; ic < 32; ++ic) {
        h2t v = __builtin_bit_cast(h2t, p[(size_t)ic * 4096]);
        sx += (float)v.x; sy += (float)v.y;
    }
    red[qc][jl] = make_float2(sx, sy);
    __syncthreads();
    if (t < 64) {
        const int jj = jb + t;
        float2 a0 = red[0][t], a1 = red[1][t], a2 = red[2][t], a3 = red[3][t];
        const float tx = a0.x + a1.x + a2.x + a3.x;
        const float ty = a0.y + a1.y + a2.y + a3.y;
        if constexpr (RMODE == 0) {
            S0out[2 * jj]     = tx;
            S0out[2 * jj + 1] = ty;
            const float vx = tx * (1.0f / 32.0f), vy = ty * (1.0f / 32.0f);
            float sq = vx * vx + vy * vy;
#pragma unroll
            for (int mask = 4; mask >= 1; mask >>= 1) sq += __shfl_xor(sq, mask);
            const float sc = sqrtf(sq) / (1.0f + sq);
            Vout[2 * jj]     = vx * sc;
            Vout[2 * jj + 1] = vy * sc;
        } else if constexpr (RMODE == 1) {
            const float v0x = S0red[2 * jj] * (1.0f / 32.0f);
            const float v0y = S0red[2 * jj + 1] * (1.0f / 32.0f);
            float sq0 = v0x * v0x + v0y * v0y;
#pragma unroll
            for (int mask = 4; mask >= 1; mask >>= 1) sq0 += __shfl_xor(sq0, mask);
            const float sc0 = sqrtf(sq0) / (1.0f + sq0);
            float sq1 = tx * tx + ty * ty;
#pragma unroll
            for (int mask = 4; mask >= 1; mask >>= 1) sq1 += __shfl_xor(sq1, mask);
            const float sc1 = sqrtf(sq1) / (1.0f + sq1);
            Vout[2 * jj]     = fmaf(v0x, sc0, tx * sc1);
            Vout[2 * jj + 1] = fmaf(v0y, sc0, ty * sc1);
        } else {
            float sq = tx * tx + ty * ty;
#pragma unroll
            for (int mask = 4; mask >= 1; mask >>= 1) sq += __shfl_xor(sq, mask);
            const float sc = sqrtf(sq) / (1.0f + sq);
            Vout[2 * jj]     = tx * sc;
            Vout[2 * jj + 1] = ty * sc;
        }
    }
}

// ===========================================================================
// Fallback (small ws): proven R1-style f32 atomic path.
// ===========================================================================
template<int VMODE>
__global__ __launch_bounds__(256, 4)
void caps_pass_f32(const float* __restrict__ X,
                   const float* __restrict__ Wg,
                   const float* __restrict__ S0,
                   const float* __restrict__ S1,
                   float* __restrict__ Sout)
{
    constexpr int IC = 8;
    __shared__ float Ws[8192];
    __shared__ float Xs[2048];

    const int t   = threadIdx.x;
    const int kk  = t & 31;
    const int oh  = (t >> 5) & 1;
    const int bq4 = t >> 6;

    const int wg     = blockIdx.x;
    const int xcd    = wg & 7;
    const int slot   = wg >> 3;
    const int ichunk = xcd * 32 + (slot >> 2);
    const int bg     = slot & 3;
    const int i0 = ichunk * IC;
    const int b0 = bg * 16;

    float s_acc[4][8];
#pragma unroll
    for (int bb = 0; bb < 4; ++bb)
#pragma unroll
        for (int o = 0; o < 8; ++o) s_acc[bb][o] = 0.f;

    float v_r[4][8];
    if constexpr (VMODE >= 1) {
#pragma unroll
        for (int bb = 0; bb < 4; ++bb) {
            const int b = b0 + bq4 * 4 + bb;
            const float* p0 = S0 + ((size_t)b * NK + kk) * 16 + oh * 8;
            float4 a = *(const float4*)(p0);
            float4 c = *(const float4*)(p0 + 4);
            float val0[8] = {a.x,a.y,a.z,a.w,c.x,c.y,c.z,c.w};
            float sq0 = 0.f;
#pragma unroll
            for (int o = 0; o < 8; ++o) { val0[o] *= (1.0f/32.0f); sq0 = fmaf(val0[o], val0[o], sq0); }
            sq0 += __shfl_xor(sq0, 32);
            const float sc0 = sqrtf(sq0) / (1.0f + sq0);
#pragma unroll
            for (int o = 0; o < 8; ++o) v_r[bb][o] = val0[o] * sc0;
            if constexpr (VMODE == 2) {
                const float* p1 = S1 + ((size_t)b * NK + kk) * 16 + oh * 8;
                float4 a1 = *(const float4*)(p1);
                float4 c1 = *(const float4*)(p1 + 4);
                float val1[8] = {a1.x,a1.y,a1.z,a1.w,c1.x,c1.y,c1.z,c1.w};
                float sq1 = 0.f;
#pragma unroll
                for (int o = 0; o < 8; ++o) sq1 = fmaf(val1[o], val1[o], sq1);
                sq1 += __shfl_xor(sq1, 32);
                const float sc1 = sqrtf(sq1) / (1.0f + sq1);
#pragma unroll
                for (int o = 0; o < 8; ++o) v_r[bb][o] = fmaf(val1[o], sc1, v_r[bb][o]);
            }
        }
    }

    {
        const int xb   = t >> 4;
        const int xig  = t & 7;
        const int half = (t >> 3) & 1;
        const float* xp = X + (size_t)(b0 + xb) * (NI * ND) + (size_t)(i0 + xig) * ND + half * 8;
        float4 f0 = *(const float4*)(xp);
        float4 f1 = *(const float4*)(xp + 4);
        float vals[8] = {f0.x,f0.y,f0.z,f0.w,f1.x,f1.y,f1.z,f1.w};
        const int m = (xig & 7) << 3;
#pragma unroll
        for (int jj = 0; jj < 8; ++jj) {
            const int d = half * 8 + jj;
            Xs[xig * 256 + ((16 * d + xb) ^ m)] = vals[jj];
        }
    }

    for (int ii = 0; ii < IC; ++ii) {
        const int i = i0 + ii;
        __syncthreads();
        {
            const float4* wsrc = (const float4*)(Wg + (size_t)i * 8192);
#pragma unroll
            for (int j = 0; j < 8; ++j) {
                float4 val = wsrc[t + j * 256];
                const int k = (t >> 6) + 4 * j;
                ((float4*)Ws)[k * 64 + ((t & 63) ^ (k & 7))] = val;
            }
        }
        __syncthreads();

        const int xm = (ii & 7) << 3;
        float u[4][8];
        if constexpr (VMODE >= 1) {
#pragma unroll
            for (int bb = 0; bb < 4; ++bb)
#pragma unroll
                for (int o = 0; o < 8; ++o) u[bb][o] = 0.f;
        }
#pragma unroll
        for (int d = 0; d < 16; ++d) {
            const float4 x4 = *(const float4*)(&Xs[ii * 256 + ((16 * d + 4 * bq4) ^ xm)]);
            float wvv[8];
            {
                const float4 wA = ((const float4*)Ws)[kk * 64 + ((d * 4 + oh * 2)     ^ (kk & 7))];
                const float4 wB = ((const float4*)Ws)[kk * 64 + ((d * 4 + oh * 2 + 1) ^ (kk & 7))];
                wvv[0]=wA.x; wvv[1]=wA.y; wvv[2]=wA.z; wvv[3]=wA.w;
                wvv[4]=wB.x; wvv[5]=wB.y; wvv[6]=wB.z; wvv[7]=wB.w;
            }
            if constexpr (VMODE >= 1) {
#pragma unroll
                for (int o = 0; o < 8; ++o) {
                    u[0][o] = fmaf(x4.x, wvv[o], u[0][o]);
                    u[1][o] = fmaf(x4.y, wvv[o], u[1][o]);
                    u[2][o] = fmaf(x4.z, wvv[o], u[2][o]);
                    u[3][o] = fmaf(x4.w, wvv[o], u[3][o]);
                }
            } else {
#pragma unroll
                for (int o = 0; o < 8; ++o) {
                    s_acc[0][o] = fmaf(x4.x, wvv[o], s_acc[0][o]);
                    s_acc[1][o] = fmaf(x4.y, wvv[o], s_acc[1][o]);
                    s_acc[2][o] = fmaf(x4.z, wvv[o], s_acc[2][o]);
                    s_acc[3][o] = fmaf(x4.w, wvv[o], s_acc[3][o]);
                }
            }
        }

        if constexpr (VMODE >= 1) {
#pragma unroll
            for (int bb = 0; bb < 4; ++bb) {
                float lg = 0.f;
#pragma unroll
                for (int o = 0; o < 8; ++o) lg = fmaf(u[bb][o], v_r[bb][o], lg);
                lg += __shfl_xor(lg, 32);
                float m = lg;
#pragma unroll
                for (int mask = 16; mask >= 1; mask >>= 1)
                    m = fmaxf(m, __shfl_xor(m, mask));
                const float e = __expf(lg - m);
                float ssum = e;
#pragma unroll
                for (int mask = 16; mask >= 1; mask >>= 1)
                    ssum += __shfl_xor(ssum, mask);
                const float c = e / ssum;
#pragma unroll
                for (int o = 0; o < 8; ++o)
                    s_acc[bb][o] = fmaf(c, u[bb][o], s_acc[bb][o]);
            }
        }
    }

#pragma unroll
    for (int bb = 0; bb < 4; ++bb) {
        float* sp = Sout + ((size_t)(b0 + bq4 * 4 + bb) * NK + kk) * 16 + oh * 8;
#pragma unroll
        for (int o = 0; o < 8; ++o) atomicAdd(sp + o, s_acc[bb][o]);
    }
}

__global__ __launch_bounds__(256)
void squash_kernel(const float* __restrict__ S, float* __restrict__ Vout)
{
    const int idx = blockIdx.x * 256 + threadIdx.x;
    float val = S[idx];
    float sq = val * val;
#pragma unroll
    for (int mask = 8; mask >= 1; mask >>= 1) sq += __shfl_xor(sq, mask);
    const float sc = sqrtf(sq) / (1.0f + sq);
    Vout[idx] = val * sc;
}

extern "C" void kernel_launch(void* const* d_in, const int* in_sizes, int n_in,
                              void* d_out, int out_size, void* d_ws, size_t ws_size,
                              hipStream_t stream)
{
    const float* X  = (const float*)d_in[0];   // [64][2048][16]
    const float* Wg = (const float*)d_in[1];   // [2048][32][16][16]
    float* out = (float*)d_out;                // [64][32][16]

    const size_t WHU   = (size_t)2048 * 4096;       // u32
    const size_t XHU   = (size_t)64 * 2048 * 8;     // u32
    const size_t PARTU = (size_t)512 * 4096;        // u32 (f16-pair partials)
    const size_t need  = (WHU + XHU + PARTU) * 4 + 3 * 32768 * 4;  // ~44.5 MB

    const dim3 blk(256), pgrid(512), rgrid(256);

    if (ws_size >= need) {
        uint32_t* Wh   = (uint32_t*)d_ws;
        uint32_t* XT   = Wh + WHU;
        uint32_t* part = XT + XHU;
        float* s0      = (float*)(part + PARTU);
        float* v0      = s0 + 32768;
        float* v01     = v0 + 32768;

        conv_w<<<dim3(2048), blk, 0, stream>>>(Wg, Wh);
        conv_x<<<dim3(512),  blk, 0, stream>>>(X, XT);

        caps_pass_m<0><<<pgrid, blk, 0, stream>>>(XT, Wh, nullptr, part);
        caps_reduce<0><<<rgrid, blk, 0, stream>>>(part, nullptr, s0, v0);
        caps_pass_m<1><<<pgrid, blk, 0, stream>>>(XT, Wh, v0, part);
        caps_reduce<1><<<rgrid, blk, 0, stream>>>(part, s0, nullptr, v01);
        caps_pass_m<1><<<pgrid, blk, 0, stream>>>(XT, Wh, v01, part);
        caps_reduce<2><<<rgrid, blk, 0, stream>>>(part, nullptr, nullptr, out);
    } else {
        // fallback: f32 atomic path
        float* s0 = (float*)d_ws;
        float* s1 = s0 + 32768;
        float* s2 = s1 + 32768;
        hipMemsetAsync(d_ws, 0, (size_t)3 * 32768 * sizeof(float), stream);
        caps_pass_f32<0><<<dim3(1024), blk, 0, stream>>>(X, Wg, nullptr, nullptr, s0);
        caps_pass_f32<1><<<dim3(1024), blk, 0, stream>>>(X, Wg, s0, nullptr, s1);
        caps_pass_f32<2><<<dim3(1024), blk, 0, stream>>>(X, Wg, s0, s1, s2);
        squash_kernel<<<dim3(128), blk, 0, stream>>>(s2, out);
    }
}

// Round 13
// 93.445 us; speedup vs baseline: 3.6496x; 1.0349x over previous
//
#include <hip/hip_runtime.h>
#include <math.h>
#include <stdint.h>

// Problem constants
#define NB 64       // batch
#define NI 2048     // input capsules
#define NK 32       // output capsules
#define ND 16       // in_dim = out_dim

typedef _Float16 h2t   __attribute__((ext_vector_type(2)));
typedef _Float16 f16x4 __attribute__((ext_vector_type(4)));
typedef float    f32x4 __attribute__((ext_vector_type(4)));

#if defined(__has_builtin)
#if __has_builtin(__builtin_amdgcn_global_load_lds)
#define HAVE_GLL 1
#endif
#endif
#ifndef HAVE_GLL
#define HAVE_GLL 0
#endif

static __device__ __forceinline__ uint32_t pack_h2(float a, float b) {
    h2t p; p.x = (_Float16)a; p.y = (_Float16)b;
    return __builtin_bit_cast(uint32_t, p);
}

// lane ^ 16 exchange (within 32-lane halves) on the DS pipe
static __device__ __forceinline__ float swz_xor16(float x) {
    int v = __builtin_amdgcn_ds_swizzle(__builtin_bit_cast(int, x), 0x401F);
    return __builtin_bit_cast(float, v);
}
// full reduction over the 4 lane-quadrant groups (o-fragments)
static __device__ __forceinline__ float xreduce_o(float p) {
    p += swz_xor16(p);        // q ^= 1
    p += __shfl_xor(p, 32);   // q ^= 2
    return p;
}

// ---------------------------------------------------------------------------
// conv_wx: fused W and X conversion (one launch).
// Blocks [0,2048): W f32 [2048][32][16][16] -> MFMA A-frag f16 units.
//   Unit (8B) at Wh2[i*2048 + T*64 + l] = { W[i][T][4q+j][r] : j=0..3 } f16,
//   q=l>>4, r=l&15  (A[m=o][k=d] layout for v_mfma_f32_16x16x16f16).
// Blocks [2048,2560): X f32 [64][2048][16] -> XT f16 d-pair [2048][64][8].
// ---------------------------------------------------------------------------
__global__ __launch_bounds__(256)
void conv_wx(const float* __restrict__ Wg, uint32_t* __restrict__ Wh,
             const float* __restrict__ X,  uint32_t* __restrict__ XT)
{
    __shared__ float tile[32 * 264];
    const int t = threadIdx.x;
    if (blockIdx.x < 2048) {
        const int i = blockIdx.x;           // 0..2047
        const float4* src = (const float4*)(Wg + (size_t)i * 8192);
#pragma unroll
        for (int j = 0; j < 8; ++j) {
            const int f4 = t + j * 256;
            const int k  = f4 >> 6;
            const int r4 = f4 & 63;
            *(float4*)(&tile[k * 264 + r4 * 4]) = src[f4];
        }
        __syncthreads();
        const int T  = t >> 3;              // 0..31 (k-tile)
        const int l0 = (t & 7) * 8;
        const float* s = tile + T * 264;
        uint2* dst = (uint2*)(Wh + (size_t)i * 4096) + T * 64 + l0;
#pragma unroll
        for (int n = 0; n < 8; ++n) {
            const int l = l0 + n;
            const int q = l >> 4, r = l & 15;
            uint2 u;
            u.x = pack_h2(s[(4 * q + 0) * 16 + r], s[(4 * q + 1) * 16 + r]);
            u.y = pack_h2(s[(4 * q + 2) * 16 + r], s[(4 * q + 3) * 16 + r]);
            dst[n] = u;
        }
    } else {
        const int g = (blockIdx.x - 2048) * 256 + t;   // 0..131071
        const int b = g >> 11, i = g & 2047;
        const float4* src = (const float4*)(X + ((size_t)b * 2048 + i) * 16);
        const float4 f0 = src[0], f1 = src[1], f2 = src[2], f3 = src[3];
        uint4 o0, o1;
        o0.x = pack_h2(f0.x, f0.y); o0.y = pack_h2(f0.z, f0.w);
        o0.z = pack_h2(f1.x, f1.y); o0.w = pack_h2(f1.z, f1.w);
        o1.x = pack_h2(f2.x, f2.y); o1.y = pack_h2(f2.z, f2.w);
        o1.z = pack_h2(f3.x, f3.y); o1.w = pack_h2(f3.z, f3.w);
        uint4* dst = (uint4*)(XT + (size_t)i * 512 + b * 8);
        dst[0] = o0; dst[1] = o1;
    }
}

// ---------------------------------------------------------------------------
// MFMA fused routing pass — pair-tile staging, per-i softmax.
// Ring-2 of 32 KB double-slots (2 W tiles each); 8 runtime loop iterations
// (NOT unrolled — R11's full unroll caused scratch spills), 2 i's per iter.
// Per iter: [vmcnt wait pair landed][s_barrier][issue pair j+1 into freed
// slot][compute i_a fully (R9-identical softmax, own BAR_E)][compute i_b].
// Wave w owns k-tiles [8w,8w+8); C-regs lane(q=l>>4,r=l&15).
// Partials f16-pair-packed: part_h[slab][b16][k32][op8], slab=bg*128+ichunk.
// ---------------------------------------------------------------------------
template<int VMODE>
__global__ __launch_bounds__(256, 2)
void caps_pass_m(const uint32_t* __restrict__ XT,   // [2048][64][8] u32
                 const uint32_t* __restrict__ Wh,   // [2048][4096] u32 frag tiles
                 const float* __restrict__ V,       // [64][32][16] (VMODE=1)
                 uint32_t* __restrict__ part_h)     // f16-pair partials
{
    constexpr int IC = 16;
    constexpr int NP = IC / 2;          // 8 pair-iterations
    __shared__ uint32_t Ws[2][2][4096]; // 2 slots x 2 tiles x 16 KB
    __shared__ uint32_t Xs[2048];       // [ig16][b16][dp8] 8 KB
    __shared__ float    Ep[2][4][16];   // per-i-in-pair, per-wave esum partials

    const int t = threadIdx.x;
    const int l = t & 63;
    const int w = t >> 6;              // wave id -> k-tiles [8w, 8w+8)
    const int r = l & 15;              // b-in-block
    const int q = l >> 4;              // o-quad

    const int wg     = blockIdx.x;     // 0..511
    const int xcd    = wg & 7;
    const int slot   = wg >> 3;        // 0..63
    const int ichunk = xcd * 16 + (slot >> 2);   // 0..127
    const int bg     = slot & 3;
    const int i0 = ichunk * IC;
    const int b0 = bg * 16;

    f32x4 s_acc[8];
#pragma unroll
    for (int tt = 0; tt < 8; ++tt) s_acc[tt] = (f32x4){0.f, 0.f, 0.f, 0.f};

    f32x4 v_r[8];
    if constexpr (VMODE == 1) {
#pragma unroll
        for (int tt = 0; tt < 8; ++tt)
            v_r[tt] = *(const f32x4*)(V + ((size_t)(b0 + r) * NK + (8 * w + tt)) * 16 + 4 * q);
    }

    // ---- stage X chunk: Xs[ig][b][dp] (8 KB) ----
    {
        const int ig = t >> 4, uu = t & 15;
        const uint4* src = (const uint4*)(XT + (size_t)(i0 + ig) * 512 + b0 * 8);
        *(uint4*)&Xs[ig * 128 + uu * 4]        = src[uu];
        *(uint4*)&Xs[ig * 128 + (uu + 16) * 4] = src[uu + 16];
    }

    // stage one W tile into Ws[sl][half] (4 loads / thread)
#if HAVE_GLL
#define STAGE_T(sl, half, tile)                                                \
    {                                                                          \
        const size_t ibase_ = (size_t)(tile) * 4096;                           \
        _Pragma("unroll")                                                      \
        for (int jj = 0; jj < 4; ++jj) {                                       \
            const int p = w * 4 + jj;                                          \
            __builtin_amdgcn_global_load_lds(                                  \
                (const __attribute__((address_space(1))) void*)(Wh + ibase_ + p * 256 + l * 4), \
                (__attribute__((address_space(3))) void*)&Ws[sl][half][p * 256], 16, 0, 0); \
        }                                                                      \
    }
#define BAR_W(n) asm volatile("s_waitcnt vmcnt(" #n ")\ns_barrier" ::: "memory");
#else
#define STAGE_T(sl, half, tile)                                                \
    {                                                                          \
        const size_t ibase_ = (size_t)(tile) * 4096;                           \
        _Pragma("unroll")                                                      \
        for (int jj = 0; jj < 4; ++jj) {                                       \
            const int p = w * 4 + jj;                                          \
            ((uint4*)&Ws[sl][half][p * 256])[l] = *(const uint4*)(Wh + ibase_ + p * 256 + l * 4); \
        }                                                                      \
    }
#define BAR_W(n) asm volatile("s_waitcnt vmcnt(0) lgkmcnt(0)\ns_barrier" ::: "memory");
#endif
#define BAR_E() asm volatile("s_waitcnt lgkmcnt(0)\ns_barrier" ::: "memory");

    __syncthreads();   // Xs visible; clean vmcnt point

    // prologue: pair 0 -> slot 0, pair 1 -> slot 1
    STAGE_T(0, 0, i0 + 0) STAGE_T(0, 1, i0 + 1)
    STAGE_T(1, 0, i0 + 2) STAGE_T(1, 1, i0 + 3)

    for (int j = 0; j < NP; ++j) {      // runtime loop — do NOT unroll
        const int s = j & 1;
        // gate: this iter's pair landed. j=0: 16 outstanding, keep pair1's 8.
        if (j == 0) { BAR_W(8) } else { BAR_W(0) }

        // issue pair j+1 into the slot freed by iter j-1
        if (j >= 1 && j + 1 < NP) {
            const int ns = s ^ 1;
            const int nt = i0 + 2 * (j + 1);
            STAGE_T(ns, 0, nt) STAGE_T(ns, 1, nt + 1)
        }

#pragma unroll
        for (int ia = 0; ia < 2; ++ia) {
            const int ii = 2 * j + ia;
            const f16x4 xb = *(const f16x4*)&Xs[ii * 128 + r * 8 + q * 2];

            if constexpr (VMODE == 0) {
#pragma unroll
                for (int tt = 0; tt < 8; ++tt) {
                    const f16x4 a = *(const f16x4*)&Ws[s][ia][(w * 8 + tt) * 128 + l * 2];
                    s_acc[tt] = __builtin_amdgcn_mfma_f32_16x16x16f16(a, xb, s_acc[tt], 0, 0, 0);
                }
            } else {
                f32x4 um[8];
#pragma unroll
                for (int tt = 0; tt < 8; ++tt) {
                    const f16x4 a = *(const f16x4*)&Ws[s][ia][(w * 8 + tt) * 128 + l * 2];
                    um[tt] = __builtin_amdgcn_mfma_f32_16x16x16f16(
                        a, xb, (f32x4){0.f, 0.f, 0.f, 0.f}, 0, 0, 0);
                }
                // ---- logits + exp + per-wave esum partial (R9-identical) ----
                float e[8];
                float esp = 0.f;
#pragma unroll
                for (int tt = 0; tt < 8; ++tt) {
                    float p = um[tt][0] * v_r[tt][0];
                    p = fmaf(um[tt][1], v_r[tt][1], p);
                    p = fmaf(um[tt][2], v_r[tt][2], p);
                    p = fmaf(um[tt][3], v_r[tt][3], p);
                    p = xreduce_o(p);                 // full sum over o
                    e[tt] = __expf(p);                // |lg| small: no max-sub
                    esp += e[tt];
                }
                if (q == 0) Ep[ia][w][r] = esp;
                BAR_E();                              // lgkm only: staging stays in flight
                const float es = Ep[ia][0][r] + Ep[ia][1][r]
                               + Ep[ia][2][r] + Ep[ia][3][r];
                const float ci = __builtin_amdgcn_rcpf(es);
#pragma unroll
                for (int tt = 0; tt < 8; ++tt) {
                    const float c = e[tt] * ci;
                    s_acc[tt][0] = fmaf(c, um[tt][0], s_acc[tt][0]);
                    s_acc[tt][1] = fmaf(c, um[tt][1], s_acc[tt][1]);
                    s_acc[tt][2] = fmaf(c, um[tt][2], s_acc[tt][2]);
                    s_acc[tt][3] = fmaf(c, um[tt][3], s_acc[tt][3]);
                }
            }
        }
    }
#undef STAGE_T
#undef BAR_W
#undef BAR_E

    // ---- store f16-pair partial tile: part_h[slab][b=r][k=8w+tt][op=2q,2q+1] ----
    uint32_t* base = part_h + (size_t)(bg * 128 + ichunk) * 4096 + r * 256 + 2 * q;
#pragma unroll
    for (int tt = 0; tt < 8; ++tt) {
        uint2 st;
        st.x = pack_h2(s_acc[tt][0], s_acc[tt][1]);
        st.y = pack_h2(s_acc[tt][2], s_acc[tt][3]);
        *(uint2*)(base + (8 * w + tt) * 8) = st;
    }
}

// ---------------------------------------------------------------------------
// Reduce 128 f16-pair slabs per output pair + fused squash / v production.
// Output pair j in [0,16384): b=j>>8, k=(j>>3)&31, op=j&7 (o=2op,2op+1).
// RMODE=0: s0 = sum; store s0 (f32); v0 = squash(s0/32)
// RMODE=1: v01 = squash(S0red/32) + squash(sum)
// RMODE=2: out = squash(sum)
// ---------------------------------------------------------------------------
template<int RMODE>
__global__ __launch_bounds__(256)
void caps_reduce(const uint32_t* __restrict__ part_h,
                 const float* __restrict__ S0red,
                 float* __restrict__ S0out,
                 float* __restrict__ Vout)
{
    __shared__ float2 red[4][64];
    const int t   = threadIdx.x;
    const int jl  = t & 63;
    const int qc  = t >> 6;
    const int jb  = blockIdx.x * 64;     // pair base
    const int j   = jb + jl;             // 0..16383
    const int b   = j >> 8;
    const int bg  = b >> 4;
    const int loc = (b & 15) * 256 + (j & 255);
    const uint32_t* p = part_h + ((size_t)(bg * 128 + qc * 32)) * 4096 + loc;
    float sx = 0.f, sy = 0.f;
#pragma unroll 8
    for (int ic = 0; ic < 32; ++ic) {
        h2t v = __builtin_bit_cast(h2t, p[(size_t)ic * 4096]);
        sx += (float)v.x; sy += (float)v.y;
    }
    red[qc][jl] = make_float2(sx, sy);
    __syncthreads();
    if (t < 64) {
        const int jj = jb + t;
        float2 a0 = red[0][t], a1 = red[1][t], a2 = red[2][t], a3 = red[3][t];
        const float tx = a0.x + a1.x + a2.x + a3.x;
        const float ty = a0.y + a1.y + a2.y + a3.y;
        if constexpr (RMODE == 0) {
            S0out[2 * jj]     = tx;
            S0out[2 * jj + 1] = ty;
            const float vx = tx * (1.0f / 32.0f), vy = ty * (1.0f / 32.0f);
            float sq = vx * vx + vy * vy;
#pragma unroll
            for (int mask = 4; mask >= 1; mask >>= 1) sq += __shfl_xor(sq, mask);
            const float sc = sqrtf(sq) / (1.0f + sq);
            Vout[2 * jj]     = vx * sc;
            Vout[2 * jj + 1] = vy * sc;
        } else if constexpr (RMODE == 1) {
            const float v0x = S0red[2 * jj] * (1.0f / 32.0f);
            const float v0y = S0red[2 * jj + 1] * (1.0f / 32.0f);
            float sq0 = v0x * v0x + v0y * v0y;
#pragma unroll
            for (int mask = 4; mask >= 1; mask >>= 1) sq0 += __shfl_xor(sq0, mask);
            const float sc0 = sqrtf(sq0) / (1.0f + sq0);
            float sq1 = tx * tx + ty * ty;
#pragma unroll
            for (int mask = 4; mask >= 1; mask >>= 1) sq1 += __shfl_xor(sq1, mask);
            const float sc1 = sqrtf(sq1) / (1.0f + sq1);
            Vout[2 * jj]     = fmaf(v0x, sc0, tx * sc1);
            Vout[2 * jj + 1] = fmaf(v0y, sc0, ty * sc1);
        } else {
            float sq = tx * tx + ty * ty;
#pragma unroll
            for (int mask = 4; mask >= 1; mask >>= 1) sq += __shfl_xor(sq, mask);
            const float sc = sqrtf(sq) / (1.0f + sq);
            Vout[2 * jj]     = tx * sc;
            Vout[2 * jj + 1] = ty * sc;
        }
    }
}

// ===========================================================================
// Fallback (small ws): proven R1-style f32 atomic path.
// ===========================================================================
template<int VMODE>
__global__ __launch_bounds__(256, 4)
void caps_pass_f32(const float* __restrict__ X,
                   const float* __restrict__ Wg,
                   const float* __restrict__ S0,
                   const float* __restrict__ S1,
                   float* __restrict__ Sout)
{
    constexpr int IC = 8;
    __shared__ float Ws[8192];
    __shared__ float Xs[2048];

    const int t   = threadIdx.x;
    const int kk  = t & 31;
    const int oh  = (t >> 5) & 1;
    const int bq4 = t >> 6;

    const int wg     = blockIdx.x;
    const int xcd    = wg & 7;
    const int slot   = wg >> 3;
    const int ichunk = xcd * 32 + (slot >> 2);
    const int bg     = slot & 3;
    const int i0 = ichunk * IC;
    const int b0 = bg * 16;

    float s_acc[4][8];
#pragma unroll
    for (int bb = 0; bb < 4; ++bb)
#pragma unroll
        for (int o = 0; o < 8; ++o) s_acc[bb][o] = 0.f;

    float v_r[4][8];
    if constexpr (VMODE >= 1) {
#pragma unroll
        for (int bb = 0; bb < 4; ++bb) {
            const int b = b0 + bq4 * 4 + bb;
            const float* p0 = S0 + ((size_t)b * NK + kk) * 16 + oh * 8;
            float4 a = *(const float4*)(p0);
            float4 c = *(const float4*)(p0 + 4);
            float val0[8] = {a.x,a.y,a.z,a.w,c.x,c.y,c.z,c.w};
            float sq0 = 0.f;
#pragma unroll
            for (int o = 0; o < 8; ++o) { val0[o] *= (1.0f/32.0f); sq0 = fmaf(val0[o], val0[o], sq0); }
            sq0 += __shfl_xor(sq0, 32);
            const float sc0 = sqrtf(sq0) / (1.0f + sq0);
#pragma unroll
            for (int o = 0; o < 8; ++o) v_r[bb][o] = val0[o] * sc0;
            if constexpr (VMODE == 2) {
                const float* p1 = S1 + ((size_t)b * NK + kk) * 16 + oh * 8;
                float4 a1 = *(const float4*)(p1);
                float4 c1 = *(const float4*)(p1 + 4);
                float val1[8] = {a1.x,a1.y,a1.z,a1.w,c1.x,c1.y,c1.z,c1.w};
                float sq1 = 0.f;
#pragma unroll
                for (int o = 0; o < 8; ++o) sq1 = fmaf(val1[o], val1[o], sq1);
                sq1 += __shfl_xor(sq1, 32);
                const float sc1 = sqrtf(sq1) / (1.0f + sq1);
#pragma unroll
                for (int o = 0; o < 8; ++o) v_r[bb][o] = fmaf(val1[o], sc1, v_r[bb][o]);
            }
        }
    }

    {
        const int xb   = t >> 4;
        const int xig  = t & 7;
        const int half = (t >> 3) & 1;
        const float* xp = X + (size_t)(b0 + xb) * (NI * ND) + (size_t)(i0 + xig) * ND + half * 8;
        float4 f0 = *(const float4*)(xp);
        float4 f1 = *(const float4*)(xp + 4);
        float vals[8] = {f0.x,f0.y,f0.z,f0.w,f1.x,f1.y,f1.z,f1.w};
        const int m = (xig & 7) << 3;
#pragma unroll
        for (int jj = 0; jj < 8; ++jj) {
            const int d = half * 8 + jj;
            Xs[xig * 256 + ((16 * d + xb) ^ m)] = vals[jj];
        }
    }

    for (int ii = 0; ii < IC; ++ii) {
        const int i = i0 + ii;
        __syncthreads();
        {
            const float4* wsrc = (const float4*)(Wg + (size_t)i * 8192);
#pragma unroll
            for (int j = 0; j < 8; ++j) {
                float4 val = wsrc[t + j * 256];
                const int k = (t >> 6) + 4 * j;
                ((float4*)Ws)[k * 64 + ((t & 63) ^ (k & 7))] = val;
            }
        }
        __syncthreads();

        const int xm = (ii & 7) << 3;
        float u[4][8];
        if constexpr (VMODE >= 1) {
#pragma unroll
            for (int bb = 0; bb < 4; ++bb)
#pragma unroll
                for (int o = 0; o < 8; ++o) u[bb][o] = 0.f;
        }
#pragma unroll
        for (int d = 0; d < 16; ++d) {
            const float4 x4 = *(const float4*)(&Xs[ii * 256 + ((16 * d + 4 * bq4) ^ xm)]);
            float wvv[8];
            {
                const float4 wA = ((const float4*)Ws)[kk * 64 + ((d * 4 + oh * 2)     ^ (kk & 7))];
                const float4 wB = ((const float4*)Ws)[kk * 64 + ((d * 4 + oh * 2 + 1) ^ (kk & 7))];
                wvv[0]=wA.x; wvv[1]=wA.y; wvv[2]=wA.z; wvv[3]=wA.w;
                wvv[4]=wB.x; wvv[5]=wB.y; wvv[6]=wB.z; wvv[7]=wB.w;
            }
            if constexpr (VMODE >= 1) {
#pragma unroll
                for (int o = 0; o < 8; ++o) {
                    u[0][o] = fmaf(x4.x, wvv[o], u[0][o]);
                    u[1][o] = fmaf(x4.y, wvv[o], u[1][o]);
                    u[2][o] = fmaf(x4.z, wvv[o], u[2][o]);
                    u[3][o] = fmaf(x4.w, wvv[o], u[3][o]);
                }
            } else {
#pragma unroll
                for (int o = 0; o < 8; ++o) {
                    s_acc[0][o] = fmaf(x4.x, wvv[o], s_acc[0][o]);
                    s_acc[1][o] = fmaf(x4.y, wvv[o], s_acc[1][o]);
                    s_acc[2][o] = fmaf(x4.z, wvv[o], s_acc[2][o]);
                    s_acc[3][o] = fmaf(x4.w, wvv[o], s_acc[3][o]);
                }
            }
        }

        if constexpr (VMODE >= 1) {
#pragma unroll
            for (int bb = 0; bb < 4; ++bb) {
                float lg = 0.f;
#pragma unroll
                for (int o = 0; o < 8; ++o) lg = fmaf(u[bb][o], v_r[bb][o], lg);
                lg += __shfl_xor(lg, 32);
                float m = lg;
#pragma unroll
                for (int mask = 16; mask >= 1; mask >>= 1)
                    m = fmaxf(m, __shfl_xor(m, mask));
                const float e = __expf(lg - m);
                float ssum = e;
#pragma unroll
                for (int mask = 16; mask >= 1; mask >>= 1)
                    ssum += __shfl_xor(ssum, mask);
                const float c = e / ssum;
#pragma unroll
                for (int o = 0; o < 8; ++o)
                    s_acc[bb][o] = fmaf(c, u[bb][o], s_acc[bb][o]);
            }
        }
    }

#pragma unroll
    for (int bb = 0; bb < 4; ++bb) {
        float* sp = Sout + ((size_t)(b0 + bq4 * 4 + bb) * NK + kk) * 16 + oh * 8;
#pragma unroll
        for (int o = 0; o < 8; ++o) atomicAdd(sp + o, s_acc[bb][o]);
    }
}

__global__ __launch_bounds__(256)
void squash_kernel(const float* __restrict__ S, float* __restrict__ Vout)
{
    const int idx = blockIdx.x * 256 + threadIdx.x;
    float val = S[idx];
    float sq = val * val;
#pragma unroll
    for (int mask = 8; mask >= 1; mask >>= 1) sq += __shfl_xor(sq, mask);
    const float sc = sqrtf(sq) / (1.0f + sq);
    Vout[idx] = val * sc;
}

extern "C" void kernel_launch(void* const* d_in, const int* in_sizes, int n_in,
                              void* d_out, int out_size, void* d_ws, size_t ws_size,
                              hipStream_t stream)
{
    const float* X  = (const float*)d_in[0];   // [64][2048][16]
    const float* Wg = (const float*)d_in[1];   // [2048][32][16][16]
    float* out = (float*)d_out;                // [64][32][16]

    const size_t WHU   = (size_t)2048 * 4096;       // u32
    const size_t XHU   = (size_t)64 * 2048 * 8;     // u32
    const size_t PARTU = (size_t)512 * 4096;        // u32 (f16-pair partials)
    const size_t need  = (WHU + XHU + PARTU) * 4 + 3 * 32768 * 4;  // ~44.5 MB

    const dim3 blk(256), pgrid(512), rgrid(256);

    if (ws_size >= need) {
        uint32_t* Wh   = (uint32_t*)d_ws;
        uint32_t* XT   = Wh + WHU;
        uint32_t* part = XT + XHU;
        float* s0      = (float*)(part + PARTU);
        float* v0      = s0 + 32768;
        float* v01     = v0 + 32768;

        conv_wx<<<dim3(2560), blk, 0, stream>>>(Wg, Wh, X, XT);

        caps_pass_m<0><<<pgrid, blk, 0, stream>>>(XT, Wh, nullptr, part);
        caps_reduce<0><<<rgrid, blk, 0, stream>>>(part, nullptr, s0, v0);
        caps_pass_m<1><<<pgrid, blk, 0, stream>>>(XT, Wh, v0, part);
        caps_reduce<1><<<rgrid, blk, 0, stream>>>(part, s0, nullptr, v01);
        caps_pass_m<1><<<pgrid, blk, 0, stream>>>(XT, Wh, v01, part);
        caps_reduce<2><<<rgrid, blk, 0, stream>>>(part, nullptr, nullptr, out);
    } else {
        // fallback: f32 atomic path
        float* s0 = (float*)d_ws;
        float* s1 = s0 + 32768;
        float* s2 = s1 + 32768;
        hipMemsetAsync(d_ws, 0, (size_t)3 * 32768 * sizeof(float), stream);
        caps_pass_f32<0><<<dim3(1024), blk, 0, stream>>>(X, Wg, nullptr, nullptr, s0);
        caps_pass_f32<1><<<dim3(1024), blk, 0, stream>>>(X, Wg, s0, nullptr, s1);
        caps_pass_f32<2><<<dim3(1024), blk, 0, stream>>>(X, Wg, s0, s1, s2);
        squash_kernel<<<dim3(128), blk, 0, stream>>>(s2, out);
    }
}